// Round 2
// baseline (193.720 us; speedup 1.0000x reference)
//
#include <hip/hip_runtime.h>

// MPO config
#define DLEG 16
#define IN_SIZE 4096
#define OUT_SIZE 4096
#define BATCH 2048

typedef __attribute__((ext_vector_type(8))) __bf16 bf16x8;
typedef __attribute__((ext_vector_type(4))) float f32x4;

__device__ __forceinline__ unsigned short f2bf(float f) {
  unsigned u = __float_as_uint(f);
  u += 0x7fffu + ((u >> 16) & 1u);   // round-to-nearest-even
  return (unsigned short)(u >> 16);
}

__device__ __forceinline__ void async_copy16(const void* g, void* l) {
  __builtin_amdgcn_global_load_lds(
      (const __attribute__((address_space(1))) void*)g,
      (__attribute__((address_space(3))) void*)l, 16, 0, 0);
}

// ---------------------------------------------------------------------------
// Kernel 1: convert x (2048x4096 fp32) -> bf16, row-major.
// ---------------------------------------------------------------------------
__global__ __launch_bounds__(256) void k_cvt(const float* __restrict__ x,
                                             unsigned short* __restrict__ xb) {
  const int idx = blockIdx.x * 256 + threadIdx.x;
  const float4 v = ((const float4*)x)[idx];
  ushort4 o;
  o.x = f2bf(v.x); o.y = f2bf(v.y); o.z = f2bf(v.z); o.w = f2bf(v.w);
  ((ushort4*)xb)[idx] = o;
}

// ---------------------------------------------------------------------------
// Kernel 2: build Wt2[b][col][kw] (bf16): b=(i,j) 0..255, col 0..4095, kw 0..15.
//   global k = b*16 + kw;  W[col][k] = sum_s A_b[m,n,s] * lc[kw,s,o]
//   A_b[m,n,s] = sum_r fc[i,r,m] * mc[j,r,s,n]
// One block per b (256 blocks x 256 threads). Block output = contiguous 128KB.
// Phase B results bounce through padded LDS (stride 20 -> conflict-free),
// then stream out as coalesced 16B stores.
// ---------------------------------------------------------------------------
#define OSTRIDE 20
__global__ __launch_bounds__(256) void k_build_wt(
    const float* __restrict__ fc, const float* __restrict__ mc,
    const float* __restrict__ lc, unsigned short* __restrict__ wt) {
  __shared__ __align__(16) union {
    struct { float fc_s[256]; float mc_s[4096]; } in;      // phase A inputs
    unsigned short out_s[1024 * OSTRIDE];                   // phase B staging
  } u;
  __shared__ float a_s[4096];   // A_b[m][n][s]
  const int b = blockIdx.x;     // b = i*16 + j
  const int i = b >> 4, j = b & 15;
  const int t = threadIdx.x;

  u.in.fc_s[t] = fc[i * 256 + t];
#pragma unroll
  for (int q = 0; q < 16; ++q)
    u.in.mc_s[q * 256 + t] = mc[j * 4096 + q * 256 + t];
  __syncthreads();

  {  // Phase A: thread handles (n = t>>4, s = t&15) for all m
    const int n = t >> 4, s = t & 15;
    float accm[16];
#pragma unroll
    for (int m = 0; m < 16; ++m) accm[m] = 0.f;
#pragma unroll
    for (int r = 0; r < 16; ++r) {
      const float mcv = u.in.mc_s[r * 256 + s * 16 + n];
#pragma unroll
      for (int m = 0; m < 16; ++m)
        accm[m] = fmaf(u.in.fc_s[r * 16 + m], mcv, accm[m]);
    }
#pragma unroll
    for (int m = 0; m < 16; ++m) a_s[m * 256 + n * 16 + s] = accm[m];
  }
  __syncthreads();

  // Phase B. Wave-uniform (m,n) loop => broadcast a_s reads.
  // t = kw(4b) | op(2b) | sel(2b);  sel uniform per wave.
  const int kw = t & 15, op = (t >> 4) & 3, sel = t >> 6;
  float lcr[4][16];
#pragma unroll
  for (int oo = 0; oo < 4; ++oo)
#pragma unroll
    for (int s = 0; s < 16; ++s)
      lcr[oo][s] = lc[kw * 256 + s * 16 + op * 4 + oo];

  // 4 quarters of m (4 m's -> 1024 cols each)
  for (int h = 0; h < 4; ++h) {
#pragma unroll
    for (int mm = 0; mm < 2; ++mm) {
      const int mloc = (sel >> 1) * 2 + mm;   // 0..3 within quarter
      const int m = h * 4 + mloc;
#pragma unroll
      for (int nn = 0; nn < 8; ++nn) {
        const int n = (sel & 1) * 8 + nn;
        const float4* ap = (const float4*)&a_s[m * 256 + n * 16];
        float av[16];
        ((float4*)av)[0] = ap[0];
        ((float4*)av)[1] = ap[1];
        ((float4*)av)[2] = ap[2];
        ((float4*)av)[3] = ap[3];
        float accv[4] = {0.f, 0.f, 0.f, 0.f};
#pragma unroll
        for (int s = 0; s < 16; ++s)
#pragma unroll
          for (int oo = 0; oo < 4; ++oo)
            accv[oo] = fmaf(av[s], lcr[oo][s], accv[oo]);
        const int cl = mloc * 256 + n * 16 + op * 4;   // local col in quarter
#pragma unroll
        for (int oo = 0; oo < 4; ++oo)
          u.out_s[(cl + oo) * OSTRIDE + kw] = f2bf(accv[oo]);
      }
    }
    __syncthreads();
    // coalesced writeout: quarter = 1024 cols x 16 kw = 16384 elems
    unsigned short* wtb = wt + (size_t)b * 65536 + (size_t)h * 16384;
#pragma unroll
    for (int it = 0; it < 8; ++it) {
      const int q = it * 256 + t;          // chunk of 8 elems
      const int cl = q >> 1, kwg = q & 1;
      const unsigned short* src = &u.out_s[cl * OSTRIDE + kwg * 8];
      uint2 lo = *(const uint2*)src;
      uint2 hi = *(const uint2*)(src + 4);
      uint4 v = make_uint4(lo.x, lo.y, hi.x, hi.y);
      *(uint4*)(wtb + q * 8) = v;
    }
    __syncthreads();   // out_s reused next quarter
  }
}

// ---------------------------------------------------------------------------
// Kernel 3: GEMM  out[2048,4096] = Xbf @ W + bias  (fp32 out)
// BM=BN=128, BK=32, 256 threads (4 waves 2x2), 4x4 frags of
// mfma_f32_16x16x32_bf16, global_load_lds width=16 staging.
// B source layout: Wt2[kb][col][kw] -> per k-tile two contiguous 4KB spans.
// Grid: (4096/128, 2048/128) = (32, 16)
// ---------------------------------------------------------------------------
__global__ __launch_bounds__(256) void k_gemm(
    const unsigned short* __restrict__ X,    // 2048 x 4096 (bf16 bits)
    const unsigned short* __restrict__ Wt,   // [kb=256][col=4096][kw=16]
    const float* __restrict__ bias,
    float* __restrict__ out) {
  __shared__ unsigned short As[128 * 32];  // 8KB, row-major 128x32
  __shared__ unsigned short Bs[2 * 128 * 16];  // 8KB, [kb2][col][kw]

  const int t = threadIdx.x;
  const int l = t & 63;
  const int w = t >> 6;
  const int wm = w >> 1, wn = w & 1;
  const int m0 = blockIdx.y * 128, n0 = blockIdx.x * 128;

  // A staging: chunk c covers tile row c>>2, 8-col group c&3 (16B)
  const int c0 = t, c1 = t + 256;
  const unsigned short* xg0 = X + (size_t)(m0 + (c0 >> 2)) * 4096 + (c0 & 3) * 8;
  const unsigned short* xg1 = X + (size_t)(m0 + (c1 >> 2)) * 4096 + (c1 & 3) * 8;
  unsigned short* lA0 = As + c0 * 8;
  unsigned short* lA1 = As + c1 * 8;
  // B staging: two contiguous 4KB spans per k-tile
  const unsigned short* wg0 = Wt + (size_t)n0 * 16 + t * 8;
  const unsigned short* wg1 = wg0 + 65536;
  unsigned short* lB0 = Bs + t * 8;
  unsigned short* lB1 = Bs + 2048 + t * 8;

  // fragment addressing
  const int arow = wm * 64 + (l & 15);
  const int brow = wn * 64 + (l & 15);
  const int koff = (l >> 4) * 8;
  const int bkb = koff >> 4;          // 0 or 1
  const int bkw = koff & 15;          // 0 or 8

  f32x4 acc[4][4];
#pragma unroll
  for (int a = 0; a < 4; ++a)
#pragma unroll
    for (int c = 0; c < 4; ++c) acc[a][c] = (f32x4){0.f, 0.f, 0.f, 0.f};

  for (int kt = 0; kt < 4096; kt += 32) {
    const size_t boff = (size_t)kt * 4096;   // (kt/16)*65536
    async_copy16(xg0 + kt, lA0);
    async_copy16(xg1 + kt, lA1);
    async_copy16(wg0 + boff, lB0);
    async_copy16(wg1 + boff, lB1);
    __syncthreads();  // drains vmcnt before barrier -> staging complete

    bf16x8 af[4], bfr[4];
#pragma unroll
    for (int mi = 0; mi < 4; ++mi)
      af[mi] = *(const bf16x8*)&As[(arow + mi * 16) * 32 + koff];
#pragma unroll
    for (int ni = 0; ni < 4; ++ni)
      bfr[ni] = *(const bf16x8*)&Bs[bkb * 2048 + (brow + ni * 16) * 16 + bkw];

#pragma unroll
    for (int mi = 0; mi < 4; ++mi)
#pragma unroll
      for (int ni = 0; ni < 4; ++ni)
        acc[mi][ni] = __builtin_amdgcn_mfma_f32_16x16x32_bf16(
            af[mi], bfr[ni], acc[mi][ni], 0, 0, 0);
    __syncthreads();  // protect LDS before next staging
  }

  // epilogue: C/D layout col = lane&15, row = (lane>>4)*4 + reg
#pragma unroll
  for (int ni = 0; ni < 4; ++ni) {
    const int col = n0 + wn * 64 + ni * 16 + (l & 15);
    const float bv = bias[col];
#pragma unroll
    for (int mi = 0; mi < 4; ++mi) {
      const int row = m0 + wm * 64 + mi * 16 + (l >> 4) * 4;
#pragma unroll
      for (int r = 0; r < 4; ++r)
        out[(size_t)(row + r) * 4096 + col] = acc[mi][ni][r] + bv;
    }
  }
}

// ---------------------------------------------------------------------------
extern "C" void kernel_launch(void* const* d_in, const int* in_sizes, int n_in,
                              void* d_out, int out_size, void* d_ws,
                              size_t ws_size, hipStream_t stream) {
  const float* x    = (const float*)d_in[0];
  const float* fc   = (const float*)d_in[1];
  const float* mc   = (const float*)d_in[2];
  const float* lc   = (const float*)d_in[3];
  const float* bias = (const float*)d_in[4];
  float* out = (float*)d_out;

  unsigned short* xb = (unsigned short*)d_ws;                       // 16.8 MB
  unsigned short* wt = xb + (size_t)BATCH * IN_SIZE;                // 33.6 MB

  k_cvt<<<(BATCH * IN_SIZE / 4) / 256, 256, 0, stream>>>(x, xb);
  k_build_wt<<<256, 256, 0, stream>>>(fc, mc, lc, wt);
  k_gemm<<<dim3(OUT_SIZE / 128, BATCH / 128), 256, 0, stream>>>(xb, wt, bias, out);
}